// Round 13
// baseline (123.533 us; speedup 1.0000x reference)
//
#include <hip/hip_runtime.h>
#include <hip/hip_bf16.h>

#define N 8192
#define FIN 256
#define FOUT 64
#define NSLICE 8
#define SLICE_J (N / NSLICE) /* 1024 */
#define NEG_INF -9.0e15f
#define L2E 1.4426950408889634f

typedef __attribute__((ext_vector_type(8))) short short8;
typedef __attribute__((ext_vector_type(4))) float f32x4;
typedef __attribute__((ext_vector_type(2))) int iv2;
typedef unsigned long long u64;

static __device__ __forceinline__ short f2bf(float v) {
    __hip_bfloat16 b = __float2bfloat16(v);
    return __builtin_bit_cast(short, b);
}
static __device__ __forceinline__ float bf2f(short s) {
    unsigned u = ((unsigned)(unsigned short)s) << 16;
    return __builtin_bit_cast(float, u);
}
static __device__ __forceinline__ float exp2fast(float x) {
    return __builtin_amdgcn_exp2f(x); // v_exp_f32: 2^x
}
// permuted k-order for int2-ballot staging: chunk m covers real cols
// (m>>1)*128 + 2L + (m&1); logical kg = m*64+L ->
static __device__ __forceinline__ int realcol2(int kg) {
    return (kg & ~127) + ((kg & 63) << 1) + ((kg >> 6) & 1);
}

// ---------------- k1: Wh = h @ W; s1' = (Wh@a1)*log2e; s2' = (Wh@a2)*log2e ----
__global__ __launch_bounds__(256) void k_wh(const float* __restrict__ h,
                                            const float* __restrict__ W,
                                            const float* __restrict__ a,
                                            float* __restrict__ Wh,
                                            float* __restrict__ s1,
                                            float* __restrict__ s2) {
    int wave = threadIdx.x >> 6, lane = threadIdx.x & 63;
    int i = blockIdx.x * 4 + wave;
    const float* hrow = h + (size_t)i * FIN;
    float acc = 0.f;
#pragma unroll 8
    for (int k = 0; k < FIN; k += 4) {
        float4 hv = *(const float4*)(hrow + k);
        acc += hv.x * W[(k + 0) * FOUT + lane];
        acc += hv.y * W[(k + 1) * FOUT + lane];
        acc += hv.z * W[(k + 2) * FOUT + lane];
        acc += hv.w * W[(k + 3) * FOUT + lane];
    }
    Wh[(size_t)i * FOUT + lane] = acc;
    float v1 = acc * a[lane];
    float v2 = acc * a[FOUT + lane];
#pragma unroll
    for (int off = 32; off; off >>= 1) {
        v1 += __shfl_xor(v1, off);
        v2 += __shfl_xor(v2, off);
    }
    if (lane == 0) { s1[i] = v1 * L2E; s2[i] = v2 * L2E; }
}

// ------- k2: repack Wh -> WhB (bf16 B-frag, realcol2 k-order) + fused max ----
__global__ __launch_bounds__(256) void k_repack(const float* __restrict__ Wh,
                                                short* __restrict__ WhB,
                                                const float* __restrict__ s2,
                                                float* __restrict__ maxs2) {
    int t = blockIdx.x * 256 + threadIdx.x; // 65536 total
    int lane = t & 63, ft = (t >> 6) & 3, jt = t >> 8;
    int g = lane >> 4, r = lane & 15;
    short8 w;
#pragma unroll
    for (int q = 0; q < 8; ++q) {
        int kg = jt * 32 + g * 8 + q;
        float v = Wh[(size_t)realcol2(kg) * FOUT + ft * 16 + r];
        w[q] = f2bf(v);
    }
    *((short8*)WhB + t) = w;

    // fused max_j s2[j] (block 0 only; flash launches strictly after)
    if (blockIdx.x == 0) {
        int tt = threadIdx.x;
        float m = NEG_INF;
        for (int i = tt; i < N; i += 256) m = fmaxf(m, s2[i]);
#pragma unroll
        for (int off = 32; off; off >>= 1) m = fmaxf(m, __shfl_xor(m, off));
        __shared__ float red[4];
        if ((tt & 63) == 0) red[tt >> 6] = m;
        __syncthreads();
        if (tt == 0)
            maxs2[0] = fmaxf(fmaxf(red[0], red[1]), fmaxf(red[2], red[3]));
    }
}

// ---------------- k3: FUSED flash, software-pipelined sub-tiles --------------
// Per wave: 8 sub-tiles of 128 cols. Hold one sub-tile's 16 int2 NT loads in
// regs; ballot -> 2 reg-resident u64 masks per lane (row r); issue sub-tile
// t+1's loads BEFORE computing sub-tile t -> loads in flight under all compute.
// No ldsm LDS table (wave-private masks); only s2s in LDS.
__global__ __launch_bounds__(128) void k_flash(const int* __restrict__ adj,
                                               const short* __restrict__ WhB,
                                               const float* __restrict__ s1,
                                               const float* __restrict__ s2,
                                               const float* __restrict__ maxs2,
                                               float* __restrict__ pO,
                                               float* __restrict__ pl) {
    int rb = blockIdx.x / NSLICE, sl = blockIdx.x % NSLICE;
    int wave = threadIdx.x >> 6, lane = threadIdx.x & 63;
    int r = lane & 15, g = lane >> 4;
    int row = rb * 32 + wave * 16 + r;

    __shared__ __align__(16) float s2s[SLICE_J];
    for (int t = threadIdx.x; t < SLICE_J; t += 128)
        s2s[t] = s2[realcol2(sl * SLICE_J + t)];
    __syncthreads();

    float s1i = s1[row];
    float xm = s1i + maxs2[0];
    float Mp = fmaxf(xm, 0.2f * xm); // lrelu in log2 domain (scale>0 commutes)

    float l = 0.f;
    f32x4 acc0 = {0.f, 0.f, 0.f, 0.f};
    f32x4 acc1 = {0.f, 0.f, 0.f, 0.f};
    f32x4 acc2 = {0.f, 0.f, 0.f, 0.f};
    f32x4 acc3 = {0.f, 0.f, 0.f, 0.f};

    const int* abase = adj + (size_t)(rb * 32 + wave * 16) * N + sl * SLICE_J;

    iv2 v[16];
#pragma unroll
    for (int i = 0; i < 16; ++i)
        v[i] = __builtin_nontemporal_load((const iv2*)(abase + (size_t)i * N) + lane);

#pragma unroll
    for (int t = 0; t < 8; ++t) {
        // consume held loads -> per-lane masks for row r of this sub-tile
        u64 m0, m1;
#pragma unroll
        for (int i = 0; i < 16; ++i) {
            u64 b0 = __ballot(v[i][0] > 0);
            u64 b1 = __ballot(v[i][1] > 0);
            if (r == i) { m0 = b0; m1 = b1; }
        }
        // issue next sub-tile's loads (in flight under the compute below)
        if (t < 7) {
#pragma unroll
            for (int i = 0; i < 16; ++i)
                v[i] = __builtin_nontemporal_load(
                    (const iv2*)(abase + (size_t)i * N + (t + 1) * 128) + lane);
        }
        u64 mm[2] = {m0, m1};
#pragma unroll
        for (int s = 0; s < 4; ++s) {
            unsigned bits = (unsigned)((mm[s >> 1] >>
                                        (((s & 1) << 5) + (g << 3))) & 0xffull);
            int S = t * 4 + s; // global step within slice
            float4 sv0 = *(const float4*)&s2s[S * 32 + g * 8];
            float4 sv1 = *(const float4*)&s2s[S * 32 + g * 8 + 4];

            short8 af;
            auto pc = [&](unsigned bit, float s2v) -> short {
                float x = s1i + s2v;
                float lr = fmaxf(x, 0.2f * x);  // leaky_relu (log2-scaled)
                float p = exp2fast(lr - Mp);    // exp(e - M)
                return bit ? f2bf(p) : (short)0;
            };
            af[0] = pc(bits & 1u, sv0.x);        af[1] = pc((bits >> 1) & 1u, sv0.y);
            af[2] = pc((bits >> 2) & 1u, sv0.z); af[3] = pc((bits >> 3) & 1u, sv0.w);
            af[4] = pc((bits >> 4) & 1u, sv1.x); af[5] = pc((bits >> 5) & 1u, sv1.y);
            af[6] = pc((bits >> 6) & 1u, sv1.z); af[7] = pc((bits >> 7) & 1u, sv1.w);

            l += bf2f(af[0]) + bf2f(af[1]) + bf2f(af[2]) + bf2f(af[3]) +
                 bf2f(af[4]) + bf2f(af[5]) + bf2f(af[6]) + bf2f(af[7]);

            int jt = sl * 32 + S;
            const short8* bp = (const short8*)WhB + (size_t)jt * 256 + lane;
            acc0 = __builtin_amdgcn_mfma_f32_16x16x32_bf16(af, bp[0], acc0, 0, 0, 0);
            acc1 = __builtin_amdgcn_mfma_f32_16x16x32_bf16(af, bp[64], acc1, 0, 0, 0);
            acc2 = __builtin_amdgcn_mfma_f32_16x16x32_bf16(af, bp[128], acc2, 0, 0, 0);
            acc3 = __builtin_amdgcn_mfma_f32_16x16x32_bf16(af, bp[192], acc3, 0, 0, 0);
        }
    }

    // reduce l across the 4 k-groups
    l += __shfl_xor(l, 16);
    l += __shfl_xor(l, 32);

    // write partials: C layout col=lane&15, rows (lane>>4)*4+reg
    int base_row = rb * 32 + wave * 16;
    f32x4 accs[4] = {acc0, acc1, acc2, acc3};
#pragma unroll
    for (int nt = 0; nt < 4; ++nt) {
#pragma unroll
        for (int reg = 0; reg < 4; ++reg) {
            int orow = base_row + g * 4 + reg;
            pO[((size_t)orow * NSLICE + sl) * FOUT + nt * 16 + r] = accs[nt][reg];
        }
    }
    if (lane < 16) pl[(size_t)row * NSLICE + sl] = l;
}

// ---------------- k4: merge partials (plain sum) + ELU ----------------
__global__ __launch_bounds__(256) void k_merge(const float* __restrict__ pO,
                                               const float* __restrict__ pl,
                                               float* __restrict__ out) {
    int t = blockIdx.x * 256 + threadIdx.x;
    int row = t >> 6, f = t & 63;
    float L = 0.f, O = 0.f;
#pragma unroll
    for (int s = 0; s < NSLICE; ++s) {
        L += pl[(size_t)row * NSLICE + s];
        O += pO[((size_t)row * NSLICE + s) * FOUT + f];
    }
    float x = O / L;
    out[t] = x > 0.f ? x : expm1f(x);
}

extern "C" void kernel_launch(void* const* d_in, const int* in_sizes, int n_in,
                              void* d_out, int out_size, void* d_ws, size_t ws_size,
                              hipStream_t stream) {
    const float* h   = (const float*)d_in[0];
    const int*   adj = (const int*)d_in[1];
    const float* W   = (const float*)d_in[2];
    const float* a   = (const float*)d_in[3];
    float* out = (float*)d_out;

    char* ws = (char*)d_ws;
    float* Wh    = (float*)ws;                          // 2 MB
    short* WhB   = (short*)(ws + (2u << 20));           // 1 MB
    float* s1    = (float*)(ws + (3u << 20));           // 32 KB
    float* s2    = (float*)(ws + (3u << 20) + 32768);   // 32 KB
    float* maxs2 = (float*)(ws + (3u << 20) + 65536);   // 4 B
    float* pO    = (float*)(ws + (4u << 20));           // 16 MB
    float* pl    = (float*)(ws + (20u << 20));          // 256 KB

    k_wh<<<N / 4, 256, 0, stream>>>(h, W, a, Wh, s1, s2);
    k_repack<<<(N / 32) * 4 * 64 / 256, 256, 0, stream>>>(Wh, WhB, s2, maxs2);
    k_flash<<<(N / 32) * NSLICE, 128, 0, stream>>>(adj, WhB, s1, s2, maxs2, pO, pl);
    k_merge<<<N * FOUT / 256, 256, 0, stream>>>(pO, pl, out);
}

// Round 14
// 110.829 us; speedup vs baseline: 1.1146x; 1.1146x over previous
//
#include <hip/hip_runtime.h>
#include <hip/hip_bf16.h>

#define N 8192
#define FIN 256
#define FOUT 64
#define NSLICE 8
#define SLICE_J (N / NSLICE) /* 1024 */
#define NEG_INF -9.0e15f
#define L2E 1.4426950408889634f

typedef __attribute__((ext_vector_type(8))) short short8;
typedef __attribute__((ext_vector_type(4))) float f32x4;
typedef __attribute__((ext_vector_type(4))) int iv4;
typedef unsigned long long u64;

static __device__ __forceinline__ short f2bf(float v) {
    __hip_bfloat16 b = __float2bfloat16(v);
    return __builtin_bit_cast(short, b);
}
static __device__ __forceinline__ float bf2f(short s) {
    unsigned u = ((unsigned)(unsigned short)s) << 16;
    return __builtin_bit_cast(float, u);
}
static __device__ __forceinline__ float exp2fast(float x) {
    return __builtin_amdgcn_exp2f(x); // v_exp_f32: 2^x
}
// permuted k-order: real col for logical k-index kg (int4-ballot natural order)
static __device__ __forceinline__ int realcol(int kg) {
    return (kg & ~255) + ((kg & 63) << 2) + ((kg >> 6) & 3);
}

// ---------------- k1: Wh = h @ W; s1' = (Wh@a1)*log2e; s2' = (Wh@a2)*log2e ----
__global__ __launch_bounds__(256) void k_wh(const float* __restrict__ h,
                                            const float* __restrict__ W,
                                            const float* __restrict__ a,
                                            float* __restrict__ Wh,
                                            float* __restrict__ s1,
                                            float* __restrict__ s2) {
    int wave = threadIdx.x >> 6, lane = threadIdx.x & 63;
    int i = blockIdx.x * 4 + wave;
    const float* hrow = h + (size_t)i * FIN;
    float acc = 0.f;
#pragma unroll 8
    for (int k = 0; k < FIN; k += 4) {
        float4 hv = *(const float4*)(hrow + k);
        acc += hv.x * W[(k + 0) * FOUT + lane];
        acc += hv.y * W[(k + 1) * FOUT + lane];
        acc += hv.z * W[(k + 2) * FOUT + lane];
        acc += hv.w * W[(k + 3) * FOUT + lane];
    }
    Wh[(size_t)i * FOUT + lane] = acc;
    float v1 = acc * a[lane];
    float v2 = acc * a[FOUT + lane];
#pragma unroll
    for (int off = 32; off; off >>= 1) {
        v1 += __shfl_xor(v1, off);
        v2 += __shfl_xor(v2, off);
    }
    if (lane == 0) { s1[i] = v1 * L2E; s2[i] = v2 * L2E; }
}

// ------- k2: repack Wh -> WhB (bf16 B-frag, realcol k-order) + fused max -----
__global__ __launch_bounds__(256) void k_repack(const float* __restrict__ Wh,
                                                short* __restrict__ WhB,
                                                const float* __restrict__ s2,
                                                float* __restrict__ maxs2) {
    int t = blockIdx.x * 256 + threadIdx.x; // 65536 total
    int lane = t & 63, ft = (t >> 6) & 3, jt = t >> 8;
    int g = lane >> 4, r = lane & 15;
    short8 w;
#pragma unroll
    for (int q = 0; q < 8; ++q) {
        int kg = jt * 32 + g * 8 + q;
        float v = Wh[(size_t)realcol(kg) * FOUT + ft * 16 + r];
        w[q] = f2bf(v);
    }
    *((short8*)WhB + t) = w;

    // fused max_j s2[j] (block 0 only; flash launches strictly after)
    if (blockIdx.x == 0) {
        int tt = threadIdx.x;
        float m = NEG_INF;
        for (int i = tt; i < N; i += 256) m = fmaxf(m, s2[i]);
#pragma unroll
        for (int off = 32; off; off >>= 1) m = fmaxf(m, __shfl_xor(m, off));
        __shared__ float red[4];
        if ((tt & 63) == 0) red[tt >> 6] = m;
        __syncthreads();
        if (tt == 0)
            maxs2[0] = fmaxf(fmaxf(red[0], red[1]), fmaxf(red[2], red[3]));
    }
}

// ---------------- k3: FUSED flash (R11 verbatim; bf16 partial stores) -------
// Phase 1: per wave, 16 rows x 4KB slice. Clause of 8 NT int4 loads (2 rows)
// issued BEFORE any ballot (SGPR-writing ballots fence the VMEM queue).
// Ballots -> LDS mask table ldsm[32][17]. Phase 2: permuted-mask compute.
__global__ __launch_bounds__(128) void k_flash(const int* __restrict__ adj,
                                               const short* __restrict__ WhB,
                                               const float* __restrict__ s1,
                                               const float* __restrict__ s2,
                                               const float* __restrict__ maxs2,
                                               __hip_bfloat16* __restrict__ pO,
                                               float* __restrict__ pl) {
    int rb = blockIdx.x / NSLICE, sl = blockIdx.x % NSLICE;
    int wave = threadIdx.x >> 6, lane = threadIdx.x & 63;
    int r = lane & 15, g = lane >> 4;
    int row = rb * 32 + wave * 16 + r;

    __shared__ __align__(16) float s2s[SLICE_J];
    __shared__ u64 ldsm[32][17]; // [block row][16 masks + 1 pad]

    for (int t = threadIdx.x; t < SLICE_J; t += 128) {
        s2s[t] = s2[realcol(sl * SLICE_J + t)];
    }

    // ---- Phase 1: stage adjacency masks
    const int* abase = adj + (size_t)(rb * 32 + wave * 16) * N + sl * SLICE_J;
    for (int ii = 0; ii < 8; ++ii) {
        const iv4* p0 = (const iv4*)(abase + (size_t)(2 * ii) * N) + lane;
        const iv4* p1 = (const iv4*)(abase + (size_t)(2 * ii + 1) * N) + lane;
        iv4 a0 = __builtin_nontemporal_load(p0);
        iv4 a1 = __builtin_nontemporal_load(p0 + 64);
        iv4 a2 = __builtin_nontemporal_load(p0 + 128);
        iv4 a3 = __builtin_nontemporal_load(p0 + 192);
        iv4 b0 = __builtin_nontemporal_load(p1);
        iv4 b1 = __builtin_nontemporal_load(p1 + 64);
        iv4 b2 = __builtin_nontemporal_load(p1 + 128);
        iv4 b3 = __builtin_nontemporal_load(p1 + 192);
        int lr0 = wave * 16 + 2 * ii, lr1 = lr0 + 1;
        iv4 A[4] = {a0, a1, a2, a3};
        iv4 B[4] = {b0, b1, b2, b3};
#pragma unroll
        for (int k = 0; k < 4; ++k) {
            u64 m0 = __ballot(A[k][0] > 0);
            u64 m1 = __ballot(A[k][1] > 0);
            u64 m2 = __ballot(A[k][2] > 0);
            u64 m3 = __ballot(A[k][3] > 0);
            if (lane == 0) {
                ldsm[lr0][k * 4 + 0] = m0; ldsm[lr0][k * 4 + 1] = m1;
                ldsm[lr0][k * 4 + 2] = m2; ldsm[lr0][k * 4 + 3] = m3;
            }
        }
#pragma unroll
        for (int k = 0; k < 4; ++k) {
            u64 m0 = __ballot(B[k][0] > 0);
            u64 m1 = __ballot(B[k][1] > 0);
            u64 m2 = __ballot(B[k][2] > 0);
            u64 m3 = __ballot(B[k][3] > 0);
            if (lane == 0) {
                ldsm[lr1][k * 4 + 0] = m0; ldsm[lr1][k * 4 + 1] = m1;
                ldsm[lr1][k * 4 + 2] = m2; ldsm[lr1][k * 4 + 3] = m3;
            }
        }
    }
    __syncthreads();

    // ---- Phase 2: compute
    float s1i = s1[row];
    float xm = s1i + maxs2[0];
    float Mp = fmaxf(xm, 0.2f * xm); // lrelu in log2 domain (scale>0 commutes)

    float l = 0.f;
    f32x4 acc0 = {0.f, 0.f, 0.f, 0.f};
    f32x4 acc1 = {0.f, 0.f, 0.f, 0.f};
    f32x4 acc2 = {0.f, 0.f, 0.f, 0.f};
    f32x4 acc3 = {0.f, 0.f, 0.f, 0.f};

    const u64* mrow = &ldsm[wave * 16 + r][0];

#pragma unroll
    for (int step = 0; step < SLICE_J / 32; ++step) {
        u64 ch = mrow[step >> 1];
        unsigned bits = (unsigned)((ch >> (((step & 1) << 5) + (g << 3))) & 0xffull);
        float4 sv0 = *(const float4*)&s2s[step * 32 + g * 8];
        float4 sv1 = *(const float4*)&s2s[step * 32 + g * 8 + 4];

        short8 af;
        auto pc = [&](unsigned bit, float s2v) -> short {
            float x = s1i + s2v;
            float lr = fmaxf(x, 0.2f * x);      // leaky_relu (log2-scaled domain)
            float p = exp2fast(lr - Mp);        // exp(e - M)
            return bit ? f2bf(p) : (short)0;
        };
        af[0] = pc(bits & 1u, sv0.x);        af[1] = pc((bits >> 1) & 1u, sv0.y);
        af[2] = pc((bits >> 2) & 1u, sv0.z); af[3] = pc((bits >> 3) & 1u, sv0.w);
        af[4] = pc((bits >> 4) & 1u, sv1.x); af[5] = pc((bits >> 5) & 1u, sv1.y);
        af[6] = pc((bits >> 6) & 1u, sv1.z); af[7] = pc((bits >> 7) & 1u, sv1.w);

        l += bf2f(af[0]) + bf2f(af[1]) + bf2f(af[2]) + bf2f(af[3]) +
             bf2f(af[4]) + bf2f(af[5]) + bf2f(af[6]) + bf2f(af[7]);

        int jt = sl * (SLICE_J / 32) + step;
        const short8* bp = (const short8*)WhB + (size_t)jt * 256 + lane;
        acc0 = __builtin_amdgcn_mfma_f32_16x16x32_bf16(af, bp[0], acc0, 0, 0, 0);
        acc1 = __builtin_amdgcn_mfma_f32_16x16x32_bf16(af, bp[64], acc1, 0, 0, 0);
        acc2 = __builtin_amdgcn_mfma_f32_16x16x32_bf16(af, bp[128], acc2, 0, 0, 0);
        acc3 = __builtin_amdgcn_mfma_f32_16x16x32_bf16(af, bp[192], acc3, 0, 0, 0);
    }

    // reduce l across the 4 k-groups
    l += __shfl_xor(l, 16);
    l += __shfl_xor(l, 32);

    // write partials (bf16): C layout col=lane&15, rows (lane>>4)*4+reg
    int base_row = rb * 32 + wave * 16;
    f32x4 accs[4] = {acc0, acc1, acc2, acc3};
#pragma unroll
    for (int nt = 0; nt < 4; ++nt) {
#pragma unroll
        for (int reg = 0; reg < 4; ++reg) {
            int orow = base_row + g * 4 + reg;
            pO[((size_t)orow * NSLICE + sl) * FOUT + nt * 16 + r] =
                __float2bfloat16(accs[nt][reg]);
        }
    }
    if (lane < 16) pl[(size_t)row * NSLICE + sl] = l;
}

// ---------------- k4: merge partials (plain sum, bf16 pO) + ELU -------------
__global__ __launch_bounds__(256) void k_merge(const __hip_bfloat16* __restrict__ pO,
                                               const float* __restrict__ pl,
                                               float* __restrict__ out) {
    int t = blockIdx.x * 256 + threadIdx.x;
    int row = t >> 6, f = t & 63;
    float L = 0.f, O = 0.f;
#pragma unroll
    for (int s = 0; s < NSLICE; ++s) {
        L += pl[(size_t)row * NSLICE + s];
        O += __bfloat162float(pO[((size_t)row * NSLICE + s) * FOUT + f]);
    }
    float x = O / L;
    out[t] = x > 0.f ? x : expm1f(x);
}

extern "C" void kernel_launch(void* const* d_in, const int* in_sizes, int n_in,
                              void* d_out, int out_size, void* d_ws, size_t ws_size,
                              hipStream_t stream) {
    const float* h   = (const float*)d_in[0];
    const int*   adj = (const int*)d_in[1];
    const float* W   = (const float*)d_in[2];
    const float* a   = (const float*)d_in[3];
    float* out = (float*)d_out;

    char* ws = (char*)d_ws;
    float* Wh    = (float*)ws;                          // 2 MB
    short* WhB   = (short*)(ws + (2u << 20));           // 1 MB
    float* s1    = (float*)(ws + (3u << 20));           // 32 KB
    float* s2    = (float*)(ws + (3u << 20) + 32768);   // 32 KB
    float* maxs2 = (float*)(ws + (3u << 20) + 65536);   // 4 B
    __hip_bfloat16* pO = (__hip_bfloat16*)(ws + (4u << 20)); // 8 MB
    float* pl    = (float*)(ws + (16u << 20));          // 256 KB

    k_wh<<<N / 4, 256, 0, stream>>>(h, W, a, Wh, s1, s2);
    k_repack<<<(N / 32) * 4 * 64 / 256, 256, 0, stream>>>(Wh, WhB, s2, maxs2);
    k_flash<<<(N / 32) * NSLICE, 128, 0, stream>>>(adj, WhB, s1, s2, maxs2, pO, pl);
    k_merge<<<N * FOUT / 256, 256, 0, stream>>>(pO, pl, out);
}